// Round 3
// baseline (2122.058 us; speedup 1.0000x reference)
//
#include <hip/hip_runtime.h>

// ---------------------------------------------------------------------------
// CausalSelfAttention2: x@Wqkv -> rope+scramble -> 512x block-causal attn
//                        -> o@Wo ; plus learned time-pooled qb/kb/vb outputs.
// Sizes: B=4 T=4096 C=1024 H=16 G=8 HS=64 GT=512.
// R2 fix: d_out is FLOAT32 (reference returns f32). R1/R2's identical absmax
// 31.09 == max|qb| leaking into output0's f32 region via bf16 writes.
// ---------------------------------------------------------------------------

typedef float  float4_t  __attribute__((ext_vector_type(4)));
typedef short  bfrag     __attribute__((ext_vector_type(8)));   // 8 bf16
typedef unsigned short ushort8 __attribute__((ext_vector_type(8)));

#define MFMA_BF16(A, B, C) __builtin_amdgcn_mfma_f32_16x16x32_bf16((A), (B), (C), 0, 0, 0)

__device__ __forceinline__ unsigned short f2bf(float f) {
  union { float f; unsigned u; } v; v.f = f;
  return (unsigned short)((v.u + 0x7FFFu + ((v.u >> 16) & 1u)) >> 16);   // RNE
}
__device__ __forceinline__ float bf2f(unsigned short h) {
  union { unsigned u; float f; } v; v.u = ((unsigned)h) << 16; return v.f;
}
// async global->LDS, 16B per lane; LDS dest = wave-uniform base + lane*16
__device__ __forceinline__ void async16(const void* g, void* l) {
  __builtin_amdgcn_global_load_lds(
      (const __attribute__((address_space(1))) unsigned int*)(unsigned long long)g,
      (__attribute__((address_space(3))) unsigned int*)(unsigned long long)l,
      16, 0, 0);
}

// ---------------------------------------------------------------------------
// f32 -> bf16 convert (8 elems/thread)
__global__ __launch_bounds__(256) void cvt_kernel(const float* __restrict__ in,
                                                  unsigned short* __restrict__ out, int n8) {
  int i = blockIdx.x * 256 + threadIdx.x;
  if (i >= n8) return;
  const float4_t* p = (const float4_t*)in + (size_t)i * 2;
  float4_t a = p[0], c = p[1];
  ushort8 r;
  r[0] = f2bf(a[0]); r[1] = f2bf(a[1]); r[2] = f2bf(a[2]); r[3] = f2bf(a[3]);
  r[4] = f2bf(c[0]); r[5] = f2bf(c[1]); r[6] = f2bf(c[2]); r[7] = f2bf(c[3]);
  *((ushort8*)out + i) = r;
}

// out[n][k] = bf16(in[k][n]);  in is [R,C] f32, out is [C,R] bf16
__global__ void transpose_cvt_kernel(const float* __restrict__ in,
                                     unsigned short* __restrict__ out, int R, int C) {
  __shared__ float t[32][33];
  int bc = blockIdx.x * 32, br = blockIdx.y * 32;
  int x = threadIdx.x, y = threadIdx.y;
  for (int i = 0; i < 32; i += 8) t[y + i][x] = in[(size_t)(br + y + i) * C + bc + x];
  __syncthreads();
  for (int i = 0; i < 32; i += 8) out[(size_t)(bc + y + i) * R + br + x] = f2bf(t[x][y + i]);
}

// ---------------------------------------------------------------------------
// Shared GEMM core: C128x128 tile, BK=32, 4 waves (each 64x64 = 4x4 mfma frags)
// A [M,K] bf16 row-major, BT [N,K] bf16 row-major. XOR-swizzled LDS (2-way max).
__device__ __forceinline__ void gemm_core(const unsigned short* __restrict__ A,
                                          const unsigned short* __restrict__ BT,
                                          int bm0, int bn0, int K,
                                          unsigned short* As, unsigned short* Bs,
                                          float4_t acc[4][4]) {
  int tid = threadIdx.x, w = tid >> 6;
  int lane = tid & 63, quad = lane >> 4, l16 = lane & 15;
  int wm = w >> 1, wn = w & 1;
  int rr = tid >> 2, xx = tid & 3;
  for (int k0 = 0; k0 < K; k0 += 32) {
    __syncthreads();
    {
      int r0 = rr,       s0 = xx ^ ((r0 >> 1) & 3);
      int r1 = rr + 64,  s1 = xx ^ ((r1 >> 1) & 3);
      async16(&A [(size_t)(bm0 + r0) * K + k0 + s0 * 8], &As[(size_t)(w * 64) * 8]);
      async16(&A [(size_t)(bm0 + r1) * K + k0 + s1 * 8], &As[(size_t)(256 + w * 64) * 8]);
      async16(&BT[(size_t)(bn0 + r0) * K + k0 + s0 * 8], &Bs[(size_t)(w * 64) * 8]);
      async16(&BT[(size_t)(bn0 + r1) * K + k0 + s1 * 8], &Bs[(size_t)(256 + w * 64) * 8]);
    }
    __syncthreads();
    bfrag af[4], bf_[4];
    for (int i = 0; i < 4; ++i) {
      int rm = wm * 64 + i * 16 + l16;
      af[i]  = *(const bfrag*)&As[(size_t)(rm * 4 + (quad ^ ((rm >> 1) & 3))) * 8];
      int rn = wn * 64 + i * 16 + l16;
      bf_[i] = *(const bfrag*)&Bs[(size_t)(rn * 4 + (quad ^ ((rn >> 1) & 3))) * 8];
    }
    for (int i = 0; i < 4; ++i)
      for (int j = 0; j < 4; ++j)
        acc[i][j] = MFMA_BF16(af[i], bf_[j], acc[i][j]);
  }
}

// GEMM1: qkv = x @ Wqkv, epilogue applies rope (q,k) and scatters into the
// scrambled [B,H,G,GT,HS] layouts q5/k5/v5 (bf16).
__global__ __launch_bounds__(256) void gemm1_kernel(const unsigned short* __restrict__ xb,
    const unsigned short* __restrict__ wqkvT,
    const float* __restrict__ fc, const float* __restrict__ fs,
    unsigned short* __restrict__ q5, unsigned short* __restrict__ k5,
    unsigned short* __restrict__ v5) {
  __shared__ __align__(16) unsigned short As[128 * 32];
  __shared__ __align__(16) unsigned short Bs[128 * 32];
  float4_t acc[4][4];
  for (int i = 0; i < 4; ++i) for (int j = 0; j < 4; ++j)
    acc[i][j] = (float4_t){0.f, 0.f, 0.f, 0.f};
  int bn0 = blockIdx.x * 128, bm0 = blockIdx.y * 128;
  gemm_core(xb, wqkvT, bm0, bn0, 1024, As, Bs, acc);

  int tid = threadIdx.x, w = tid >> 6, lane = tid & 63, quad = lane >> 4, l16 = lane & 15;
  int wm = w >> 1, wn = w & 1;
  for (int i = 0; i < 4; ++i)
    for (int j = 0; j < 4; ++j)
      for (int r = 0; r < 4; ++r) {
        float val = acc[i][j][r];
        float partner = __shfl_xor(val, 1);      // even<->odd channel pair
        int grow = bm0 + wm * 64 + i * 16 + quad * 4 + r;   // = b*4096 + t
        int b = grow >> 12, t = grow & 4095;
        int gcol = bn0 + wn * 64 + j * 16 + l16;            // 0..3071
        if (gcol < 2048) {                                   // q or k: rope + scramble
          int cc = gcol & 1023;
          int ho = cc >> 6, hs = cc & 63;
          float c = fc[t * 32 + (hs >> 1)], s = fs[t * 32 + (hs >> 1)];
          float roped = (hs & 1) ? fmaf(partner, s, val * c) : fmaf(-partner, s, val * c);
          // [B,H,T,HS] raw-view [B,G,GT,H,HS]: g=ho/2, gt=(ho&1)*256+t/16, h=t&15
          size_t idx = ((((size_t)b * 16 + (t & 15)) * 8 + (ho >> 1)) * 512 +
                        (((ho & 1) << 8) | (t >> 4))) * 64 + hs;
          ((gcol < 1024) ? q5 : k5)[idx] = f2bf(roped);
        } else {                                             // v: natural split
          int cc = gcol - 2048;
          size_t idx = ((((size_t)b * 16 + (cc >> 6)) * 8 + (t >> 9)) * 512 +
                        (t & 511)) * 64 + (cc & 63);
          v5[idx] = f2bf(val);
        }
      }
}

// GEMM2: out = o @ Wo, f32 store into d_out[0 .. 16777216)
__global__ __launch_bounds__(256) void gemm2_kernel(const unsigned short* __restrict__ ob,
    const unsigned short* __restrict__ woT, float* __restrict__ outp) {
  __shared__ __align__(16) unsigned short As[128 * 32];
  __shared__ __align__(16) unsigned short Bs[128 * 32];
  float4_t acc[4][4];
  for (int i = 0; i < 4; ++i) for (int j = 0; j < 4; ++j)
    acc[i][j] = (float4_t){0.f, 0.f, 0.f, 0.f};
  int bn0 = blockIdx.x * 128, bm0 = blockIdx.y * 128;
  gemm_core(ob, woT, bm0, bn0, 1024, As, Bs, acc);
  int tid = threadIdx.x, w = tid >> 6, lane = tid & 63, quad = lane >> 4, l16 = lane & 15;
  int wm = w >> 1, wn = w & 1;
  for (int i = 0; i < 4; ++i)
    for (int j = 0; j < 4; ++j)
      for (int r = 0; r < 4; ++r)
        outp[(size_t)(bm0 + wm * 64 + i * 16 + quad * 4 + r) * 1024 +
             bn0 + wn * 64 + j * 16 + l16] = acc[i][j][r];
}

// ---------------------------------------------------------------------------
// R1: transparently-correct scalar flash attention. Block = (b,h,g,qt): 64
// queries; thread t owns query q=t>>2, hs-quarter t&3 (16 output channels).
// Per-thread textbook online softmax (the 4 threads of a query compute
// identical m/l sequences after the 2-step shuffle dot reduction).
__global__ __launch_bounds__(256) void attn_simple_kernel(const unsigned short* __restrict__ q5,
    const unsigned short* __restrict__ k5, const unsigned short* __restrict__ v5,
    unsigned short* __restrict__ ob) {
  __shared__ float Ks[64 * 64];
  __shared__ float Vs[64 * 64];
  int bx = blockIdx.x;
  int qt = bx & 7, g = (bx >> 3) & 7, h = (bx >> 6) & 15, b = bx >> 10;
  int tid = threadIdx.x;
  int q = tid >> 2, quarter = tid & 3;
  size_t base = ((((size_t)b * 16 + h) * 8 + g) * 512) * 64;
  const unsigned short* Q = q5 + base;
  const unsigned short* K = k5 + base;
  const unsigned short* V = v5 + base;

  int qabs = qt * 64 + q;
  float qreg[16];
  for (int i = 0; i < 16; ++i) qreg[i] = bf2f(Q[(size_t)qabs * 64 + quarter * 16 + i]);

  float acc[16];
  for (int i = 0; i < 16; ++i) acc[i] = 0.f;
  float m = -1e30f, l = 0.f;

  for (int kt = 0; kt <= qt; ++kt) {
    __syncthreads();
    for (int i = tid; i < 4096; i += 256) {
      Ks[i] = bf2f(K[(size_t)kt * 4096 + i]);
      Vs[i] = bf2f(V[(size_t)kt * 4096 + i]);
    }
    __syncthreads();
    for (int kk = 0; kk < 64; ++kk) {
      float s = 0.f;
      for (int i = 0; i < 16; ++i) s += qreg[i] * Ks[kk * 64 + quarter * 16 + i];
      s += __shfl_xor(s, 1);
      s += __shfl_xor(s, 2);
      s *= 0.125f;
      if (kt * 64 + kk > qabs) s = -1e30f;     // causal mask
      float nm = fmaxf(m, s);
      float scale = __expf(m - nm);
      float p = __expf(s - nm);
      m = nm;
      l = l * scale + p;
      for (int i = 0; i < 16; ++i)
        acc[i] = fmaf(acc[i], scale, p * Vs[kk * 64 + quarter * 16 + i]);
    }
  }
  int orow = b * 4096 + g * 512 + qabs;
  for (int i = 0; i < 16; ++i)
    ob[(size_t)orow * 1024 + h * 64 + quarter * 16 + i] = f2bf(acc[i] / l);
}

// ---------------------------------------------------------------------------
// qb/kb/vb: weighted sums over gt (causal_attn on 1x1 == identity => vb pooled)
// f32 stores into d_out tail regions.
__global__ void pools_kernel(const unsigned short* __restrict__ q5,
    const unsigned short* __restrict__ k5, const unsigned short* __restrict__ v5,
    const float* __restrict__ qp, const float* __restrict__ kp,
    const float* __restrict__ vp, float* __restrict__ outp) {
  int g = blockIdx.x, h = blockIdx.y, b = blockIdx.z, hs = threadIdx.x;
  size_t base = ((((size_t)b * 16 + h) * 8 + g) * 512) * 64 + hs;
  float aq = 0.f, ak = 0.f, av = 0.f;
  for (int t = 0; t < 512; ++t) {
    size_t o = base + (size_t)t * 64;
    aq += bf2f(q5[o]) * qp[t];
    ak += bf2f(k5[o]) * kp[t];
    av += bf2f(v5[o]) * vp[t];
  }
  size_t oi = (((size_t)b * 16 + h) * 7 + g) * 64 + hs;
  outp[16777216 + oi] = aq;
  outp[16777216 + 28672 + oi] = ak;
  outp[16777216 + 57344 + oi] = av;
}

// ---------------------------------------------------------------------------
extern "C" void kernel_launch(void* const* d_in, const int* in_sizes, int n_in,
                              void* d_out, int out_size, void* d_ws, size_t ws_size,
                              hipStream_t stream) {
  (void)in_sizes; (void)n_in; (void)out_size; (void)ws_size;
  const float* x    = (const float*)d_in[0];
  const float* Wqkv = (const float*)d_in[1];
  const float* Wo   = (const float*)d_in[2];
  const float* qp   = (const float*)d_in[3];
  const float* kp   = (const float*)d_in[4];
  const float* vp   = (const float*)d_in[5];
  const float* fc   = (const float*)d_in[6];
  const float* fs   = (const float*)d_in[7];
  float* outp = (float*)d_out;                     // f32 output (reference dtype)

  char* ws = (char*)d_ws;                          // 136 MiB used
  unsigned short* xb    = (unsigned short*)(ws);               // 33.5MB (o aliases it later)
  unsigned short* wqkvT = (unsigned short*)(ws + 33554432);    // 6.3MB
  unsigned short* woT   = (unsigned short*)(ws + 39845888);    // 2.1MB
  unsigned short* q5    = (unsigned short*)(ws + 41943040);    // 33.5MB
  unsigned short* k5    = (unsigned short*)(ws + 75497472);    // 33.5MB
  unsigned short* v5    = (unsigned short*)(ws + 109051904);   // 33.5MB
  unsigned short* ob    = xb;  // safe alias: xb fully consumed by gemm1 before attn writes

  cvt_kernel<<<8192, 256, 0, stream>>>(x, xb, 2097152);
  transpose_cvt_kernel<<<dim3(96, 32), dim3(32, 8), 0, stream>>>(Wqkv, wqkvT, 1024, 3072);
  transpose_cvt_kernel<<<dim3(32, 32), dim3(32, 8), 0, stream>>>(Wo, woT, 1024, 1024);
  gemm1_kernel<<<dim3(24, 128), 256, 0, stream>>>(xb, wqkvT, fc, fs, q5, k5, v5);
  attn_simple_kernel<<<4096, 256, 0, stream>>>(q5, k5, v5, ob);
  pools_kernel<<<dim3(7, 16, 4), 64, 0, stream>>>(q5, k5, v5, qp, kp, vp, outp);
  gemm2_kernel<<<dim3(8, 128), 256, 0, stream>>>(ob, woT, outp);
}

// Round 6
// 568.205 us; speedup vs baseline: 3.7347x; 3.7347x over previous
//
#include <hip/hip_runtime.h>

// ---------------------------------------------------------------------------
// CausalSelfAttention2: x@Wqkv -> rope+scramble -> 512x block-causal attn
//                        -> o@Wo ; plus learned time-pooled qb/kb/vb outputs.
// Sizes: B=4 T=4096 C=1024 H=16 G=8 HS=64 GT=512. d_out is FLOAT32.
// R5 evidence: out(0) passes, qb(1) fails ~1.1 => restage PLACEMENT and MFMA
// attention are validated; only rope VALUES in the R4 read-back phase are
// wrong (rope-angle errors cancel in QK^T, show up in linear qb/kb).
// R6: rope applied BEFORE staging, in registers, with R3's exact validated
// shfl formulation; LDS read-back is scalar; vector stores kept.
// ---------------------------------------------------------------------------

typedef float  float4_t  __attribute__((ext_vector_type(4)));
typedef short  bfrag     __attribute__((ext_vector_type(8)));   // 8 bf16
typedef unsigned short ushort8 __attribute__((ext_vector_type(8)));

#define MFMA_BF16(A, B, C) __builtin_amdgcn_mfma_f32_16x16x32_bf16((A), (B), (C), 0, 0, 0)

__device__ __forceinline__ unsigned short f2bf(float f) {
  union { float f; unsigned u; } v; v.f = f;
  return (unsigned short)((v.u + 0x7FFFu + ((v.u >> 16) & 1u)) >> 16);   // RNE
}
__device__ __forceinline__ float bf2f(unsigned short h) {
  union { unsigned u; float f; } v; v.u = ((unsigned)h) << 16; return v.f;
}
// async global->LDS, 16B per lane; LDS dest = wave-uniform base + lane*16
__device__ __forceinline__ void async16(const void* g, void* l) {
  __builtin_amdgcn_global_load_lds(
      (const __attribute__((address_space(1))) unsigned int*)(unsigned long long)g,
      (__attribute__((address_space(3))) unsigned int*)(unsigned long long)l,
      16, 0, 0);
}

// ---------------------------------------------------------------------------
// f32 -> bf16 convert (8 elems/thread)
__global__ __launch_bounds__(256) void cvt_kernel(const float* __restrict__ in,
                                                  unsigned short* __restrict__ out, int n8) {
  int i = blockIdx.x * 256 + threadIdx.x;
  if (i >= n8) return;
  const float4_t* p = (const float4_t*)in + (size_t)i * 2;
  float4_t a = p[0], c = p[1];
  ushort8 r;
  r[0] = f2bf(a[0]); r[1] = f2bf(a[1]); r[2] = f2bf(a[2]); r[3] = f2bf(a[3]);
  r[4] = f2bf(c[0]); r[5] = f2bf(c[1]); r[6] = f2bf(c[2]); r[7] = f2bf(c[3]);
  *((ushort8*)out + i) = r;
}

// out[n][k] = bf16(in[k][n]);  in is [R,C] f32, out is [C,R] bf16
__global__ void transpose_cvt_kernel(const float* __restrict__ in,
                                     unsigned short* __restrict__ out, int R, int C) {
  __shared__ float t[32][33];
  int bc = blockIdx.x * 32, br = blockIdx.y * 32;
  int x = threadIdx.x, y = threadIdx.y;
  for (int i = 0; i < 32; i += 8) t[y + i][x] = in[(size_t)(br + y + i) * C + bc + x];
  __syncthreads();
  for (int i = 0; i < 32; i += 8) out[(size_t)(bc + y + i) * R + br + x] = f2bf(t[x][y + i]);
}

// ---------------------------------------------------------------------------
// Shared GEMM core: C128x128 tile, BK=32, 4 waves (each 64x64 = 4x4 mfma frags)
// A [M,K] bf16 row-major, BT [N,K] bf16 row-major. XOR-swizzled LDS (2-way max).
__device__ __forceinline__ void gemm_core(const unsigned short* __restrict__ A,
                                          const unsigned short* __restrict__ BT,
                                          int bm0, int bn0, int K,
                                          unsigned short* As, unsigned short* Bs,
                                          float4_t acc[4][4]) {
  int tid = threadIdx.x, w = tid >> 6;
  int lane = tid & 63, quad = lane >> 4, l16 = lane & 15;
  int wm = w >> 1, wn = w & 1;
  int rr = tid >> 2, xx = tid & 3;
  for (int k0 = 0; k0 < K; k0 += 32) {
    __syncthreads();
    {
      int r0 = rr,       s0 = xx ^ ((r0 >> 1) & 3);
      int r1 = rr + 64,  s1 = xx ^ ((r1 >> 1) & 3);
      async16(&A [(size_t)(bm0 + r0) * K + k0 + s0 * 8], &As[(size_t)(w * 64) * 8]);
      async16(&A [(size_t)(bm0 + r1) * K + k0 + s1 * 8], &As[(size_t)(256 + w * 64) * 8]);
      async16(&BT[(size_t)(bn0 + r0) * K + k0 + s0 * 8], &Bs[(size_t)(w * 64) * 8]);
      async16(&BT[(size_t)(bn0 + r1) * K + k0 + s1 * 8], &Bs[(size_t)(256 + w * 64) * 8]);
    }
    __syncthreads();
    bfrag af[4], bf_[4];
    for (int i = 0; i < 4; ++i) {
      int rm = wm * 64 + i * 16 + l16;
      af[i]  = *(const bfrag*)&As[(size_t)(rm * 4 + (quad ^ ((rm >> 1) & 3))) * 8];
      int rn = wn * 64 + i * 16 + l16;
      bf_[i] = *(const bfrag*)&Bs[(size_t)(rn * 4 + (quad ^ ((rn >> 1) & 3))) * 8];
    }
    for (int i = 0; i < 4; ++i)
      for (int j = 0; j < 4; ++j)
        acc[i][j] = MFMA_BF16(af[i], bf_[j], acc[i][j]);
  }
}

// GEMM1: qkv = x @ Wqkv. Rope applied in-register (R3-validated shfl form),
// then LDS restage (placement validated by R4/R5 output0) + vector stores.
__global__ __launch_bounds__(256) void gemm1_kernel(const unsigned short* __restrict__ xb,
    const unsigned short* __restrict__ wqkvT,
    const float* __restrict__ fc, const float* __restrict__ fs,
    unsigned short* __restrict__ q5, unsigned short* __restrict__ k5,
    unsigned short* __restrict__ v5) {
  __shared__ __align__(16) unsigned short As[128 * 32];
  __shared__ __align__(16) unsigned short Bs[128 * 32];
  __shared__ __align__(16) float Es[4 * 1088];               // 4 waves x (16 rows * 68)
  float4_t acc[4][4];
  for (int i = 0; i < 4; ++i) for (int j = 0; j < 4; ++j)
    acc[i][j] = (float4_t){0.f, 0.f, 0.f, 0.f};
  int bn0 = blockIdx.x * 128, bm0 = blockIdx.y * 128;
  gemm_core(xb, wqkvT, bm0, bn0, 1024, As, Bs, acc);

  int tid = threadIdx.x, w = tid >> 6, lane = tid & 63, quad = lane >> 4, l16 = lane & 15;
  int wm = w >> 1, wn = w & 1;

  // ---- rope in registers (exact R3 numerics: scalar fc/fs, shfl partner) --
  for (int i = 0; i < 4; ++i)
    for (int j = 0; j < 4; ++j) {
      int gcol = bn0 + wn * 64 + j * 16 + l16;    // wave-uniform branch (16-aligned)
      if (gcol < 2048) {
        int hs = gcol & 63;
        for (int r = 0; r < 4; ++r) {
          float val = acc[i][j][r];
          float partner = __shfl_xor(val, 1);     // even<->odd channel pair
          int t = (bm0 + wm * 64 + i * 16 + quad * 4 + r) & 4095;
          float c = fc[t * 32 + (hs >> 1)], s = fs[t * 32 + (hs >> 1)];
          acc[i][j][r] = (hs & 1) ? fmaf(partner, s, val * c)
                                  : fmaf(-partner, s, val * c);
        }
      }
    }

  // ---- LDS restage (placement-validated) + full-line vector stores --------
  float* slice = &Es[w * 1088];
  for (int i = 0; i < 4; ++i) {
    __syncthreads();   // prev iteration's reads complete before overwrite
    for (int j = 0; j < 4; ++j)
      for (int r = 0; r < 4; ++r)
        slice[(quad * 4 + r) * 68 + j * 16 + l16] = acc[i][j][r];
    __syncthreads();   // writes visible before transposed reads
    for (int m = 0; m < 2; ++m) {
      int rl = m * 8 + (lane >> 3);               // 0..15 local row
      int cb = (lane & 7) * 8;                    // 8-aligned col base
      const float* rp = &slice[rl * 68 + cb];
      ushort8 outv;
      outv[0] = f2bf(rp[0]); outv[1] = f2bf(rp[1]);
      outv[2] = f2bf(rp[2]); outv[3] = f2bf(rp[3]);
      outv[4] = f2bf(rp[4]); outv[5] = f2bf(rp[5]);
      outv[6] = f2bf(rp[6]); outv[7] = f2bf(rp[7]);
      int grow = bm0 + wm * 64 + i * 16 + rl;     // = b*4096 + t
      int b = grow >> 12, t = grow & 4095;
      int gcol = bn0 + wn * 64 + cb;              // 0..3071, 8-aligned
      if (gcol < 2048) {                          // q or k: scramble
        int cc = gcol & 1023;
        int ho = cc >> 6, hs0 = cc & 63;
        // [B,H,T,HS] raw-view [B,G,GT,H,HS]: g=ho/2, gt=(ho&1)*256+t/16, h=t&15
        size_t idx = ((((size_t)b * 16 + (t & 15)) * 8 + (ho >> 1)) * 512 +
                      (((ho & 1) << 8) | (t >> 4))) * 64 + hs0;
        if (gcol < 1024) *(ushort8*)&q5[idx] = outv;
        else             *(ushort8*)&k5[idx] = outv;
      } else {                                    // v: natural split
        int cc = gcol - 2048;
        size_t idx = ((((size_t)b * 16 + (cc >> 6)) * 8 + (t >> 9)) * 512 +
                      (t & 511)) * 64 + (cc & 63);
        *(ushort8*)&v5[idx] = outv;
      }
    }
  }
}

// GEMM2: out = o @ Wo, f32 store into d_out[0 .. 16777216)
__global__ __launch_bounds__(256) void gemm2_kernel(const unsigned short* __restrict__ ob,
    const unsigned short* __restrict__ woT, float* __restrict__ outp) {
  __shared__ __align__(16) unsigned short As[128 * 32];
  __shared__ __align__(16) unsigned short Bs[128 * 32];
  float4_t acc[4][4];
  for (int i = 0; i < 4; ++i) for (int j = 0; j < 4; ++j)
    acc[i][j] = (float4_t){0.f, 0.f, 0.f, 0.f};
  int bn0 = blockIdx.x * 128, bm0 = blockIdx.y * 128;
  gemm_core(ob, woT, bm0, bn0, 1024, As, Bs, acc);
  int tid = threadIdx.x, w = tid >> 6, lane = tid & 63, quad = lane >> 4, l16 = lane & 15;
  int wm = w >> 1, wn = w & 1;
  for (int i = 0; i < 4; ++i)
    for (int j = 0; j < 4; ++j)
      for (int r = 0; r < 4; ++r)
        outp[(size_t)(bm0 + wm * 64 + i * 16 + quad * 4 + r) * 1024 +
             bn0 + wn * 64 + j * 16 + l16] = acc[i][j][r];
}

// ---------------------------------------------------------------------------
// MFMA flash attention per (b,h,g) block of 512, 64-query tile / wg, 16 q/wave.
// Validated end-to-end by R4/R5 output-0 pass.
__global__ __launch_bounds__(256) void attn_kernel(const unsigned short* __restrict__ q5,
    const unsigned short* __restrict__ k5, const unsigned short* __restrict__ v5,
    unsigned short* __restrict__ ob) {
  __shared__ __align__(16) unsigned short Ks[32 * 64];       // swizzled 16B slots
  __shared__ __align__(16) unsigned short VTs[64 * 72];      // [hs][key], pad->72
  __shared__ __align__(16) unsigned short Ps[4 * 16 * 40];   // per-wave P, pad->40
  int bx = blockIdx.x;
  int qt = bx & 7, g = (bx >> 3) & 7, h = (bx >> 6) & 15, b = bx >> 10;
  int tid = threadIdx.x, w = tid >> 6, lane = tid & 63, quad = lane >> 4, l16 = lane & 15;
  size_t base = ((((size_t)b * 16 + h) * 8 + g) * 512) * 64;
  const unsigned short* Q = q5 + base;
  const unsigned short* K = k5 + base;
  const unsigned short* V = v5 + base;

  int qrow = qt * 64 + w * 16 + l16;
  bfrag qf0 = *(const bfrag*)&Q[(size_t)qrow * 64 + quad * 8];
  bfrag qf1 = *(const bfrag*)&Q[(size_t)qrow * 64 + 32 + quad * 8];

  float4_t acc[4];
  for (int i = 0; i < 4; ++i) acc[i] = (float4_t){0.f, 0.f, 0.f, 0.f};
  float m_i[4] = {-1e30f, -1e30f, -1e30f, -1e30f};
  float l_i[4] = {0.f, 0.f, 0.f, 0.f};

  int skey = tid >> 3, sx = tid & 7, ss = sx ^ (skey & 7);   // K staging swizzle
  unsigned short* Pw = &Ps[w * 640];
  int ntiles = qt * 2 + 2;

  for (int kt = 0; kt < ntiles; ++kt) {
    __syncthreads();
    // K tile 32x64: one async16 per thread
    async16(&K[(size_t)(kt * 32 + skey) * 64 + ss * 8], &Ks[(size_t)(w * 64) * 8]);
    // V tile transposed into VTs[hs][key] (threads 0..127, 2 keys x 8 hs each)
    if (tid < 128) {
      int kp = tid & 15, hsg = tid >> 4;
      const unsigned short* vp0 = &V[(size_t)(kt * 32 + kp * 2) * 64 + hsg * 8];
      ushort8 va = *(const ushort8*)vp0;
      ushort8 vb = *(const ushort8*)(vp0 + 64);
      for (int e = 0; e < 8; ++e) {
        unsigned pk = (unsigned)va[e] | ((unsigned)vb[e] << 16);
        *(unsigned*)&VTs[(size_t)(hsg * 8 + e) * 72 + kp * 2] = pk;
      }
    }
    __syncthreads();

    float4_t s0 = (float4_t){0.f, 0.f, 0.f, 0.f};
    float4_t s1 = (float4_t){0.f, 0.f, 0.f, 0.f};
    {
      int sl0 = l16 * 8 + (quad ^ (l16 & 7));          // hs 0..31
      s0 = MFMA_BF16(qf0, *(const bfrag*)&Ks[(size_t)sl0 * 8], s0);
      s1 = MFMA_BF16(qf0, *(const bfrag*)&Ks[(size_t)(sl0 + 128) * 8], s1);
      int sl1 = l16 * 8 + ((4 + quad) ^ (l16 & 7));    // hs 32..63
      s0 = MFMA_BF16(qf1, *(const bfrag*)&Ks[(size_t)sl1 * 8], s0);
      s1 = MFMA_BF16(qf1, *(const bfrag*)&Ks[(size_t)(sl1 + 128) * 8], s1);
    }

    int qa = qt * 64 + w * 16 + quad * 4;
    int kb0 = kt * 32 + l16;
    for (int r = 0; r < 4; ++r) {
      float v0 = s0[r] * 0.125f, v1 = s1[r] * 0.125f;
      if (kb0 > qa + r)      v0 = -1e30f;
      if (kb0 + 16 > qa + r) v1 = -1e30f;
      float tm = fmaxf(v0, v1);
      tm = fmaxf(tm, __shfl_xor(tm, 1));
      tm = fmaxf(tm, __shfl_xor(tm, 2));
      tm = fmaxf(tm, __shfl_xor(tm, 4));
      tm = fmaxf(tm, __shfl_xor(tm, 8));
      float nm = fmaxf(m_i[r], tm);
      float alpha = __expf(m_i[r] - nm);
      m_i[r] = nm;
      float p0 = __expf(v0 - nm), p1 = __expf(v1 - nm);
      float rs = p0 + p1;
      rs += __shfl_xor(rs, 1);
      rs += __shfl_xor(rs, 2);
      rs += __shfl_xor(rs, 4);
      rs += __shfl_xor(rs, 8);
      l_i[r] = l_i[r] * alpha + rs;
      acc[0][r] *= alpha; acc[1][r] *= alpha; acc[2][r] *= alpha; acc[3][r] *= alpha;
      Pw[(quad * 4 + r) * 40 + l16] = f2bf(p0);
      Pw[(quad * 4 + r) * 40 + 16 + l16] = f2bf(p1);
    }
    __syncthreads();   // P writes visible before A-frag reads
    // P (C-layout) -> A-operand frag via LDS round-trip
    bfrag pf = *(const bfrag*)&Pw[(size_t)l16 * 40 + quad * 8];
    for (int ht = 0; ht < 4; ++ht) {
      bfrag vf = *(const bfrag*)&VTs[(size_t)(ht * 16 + l16) * 72 + quad * 8];
      acc[ht] = MFMA_BF16(pf, vf, acc[ht]);
    }
  }

  // o_final[b, g*512+gt, h*64+hs]
  int orow = b * 4096 + g * 512 + qt * 64 + w * 16 + quad * 4;
  for (int ht = 0; ht < 4; ++ht)
    for (int r = 0; r < 4; ++r)
      ob[(size_t)(orow + r) * 1024 + h * 64 + ht * 16 + l16] = f2bf(acc[ht][r] / l_i[r]);
}

// ---------------------------------------------------------------------------
// qb/kb/vb: weighted sums over gt (causal_attn on 1x1 == identity => vb pooled)
// f32 stores into d_out tail regions.
__global__ void pools_kernel(const unsigned short* __restrict__ q5,
    const unsigned short* __restrict__ k5, const unsigned short* __restrict__ v5,
    const float* __restrict__ qp, const float* __restrict__ kp,
    const float* __restrict__ vp, float* __restrict__ outp) {
  int g = blockIdx.x, h = blockIdx.y, b = blockIdx.z, hs = threadIdx.x;
  size_t base = ((((size_t)b * 16 + h) * 8 + g) * 512) * 64 + hs;
  float aq = 0.f, ak = 0.f, av = 0.f;
  for (int t = 0; t < 512; ++t) {
    size_t o = base + (size_t)t * 64;
    aq += bf2f(q5[o]) * qp[t];
    ak += bf2f(k5[o]) * kp[t];
    av += bf2f(v5[o]) * vp[t];
  }
  size_t oi = (((size_t)b * 16 + h) * 7 + g) * 64 + hs;
  outp[16777216 + oi] = aq;
  outp[16777216 + 28672 + oi] = ak;
  outp[16777216 + 57344 + oi] = av;
}

// ---------------------------------------------------------------------------
extern "C" void kernel_launch(void* const* d_in, const int* in_sizes, int n_in,
                              void* d_out, int out_size, void* d_ws, size_t ws_size,
                              hipStream_t stream) {
  (void)in_sizes; (void)n_in; (void)out_size; (void)ws_size;
  const float* x    = (const float*)d_in[0];
  const float* Wqkv = (const float*)d_in[1];
  const float* Wo   = (const float*)d_in[2];
  const float* qp   = (const float*)d_in[3];
  const float* kp   = (const float*)d_in[4];
  const float* vp   = (const float*)d_in[5];
  const float* fc   = (const float*)d_in[6];
  const float* fs   = (const float*)d_in[7];
  float* outp = (float*)d_out;                     // f32 output (reference dtype)

  char* ws = (char*)d_ws;                          // 136 MiB used
  unsigned short* xb    = (unsigned short*)(ws);               // 33.5MB (o aliases it later)
  unsigned short* wqkvT = (unsigned short*)(ws + 33554432);    // 6.3MB
  unsigned short* woT   = (unsigned short*)(ws + 39845888);    // 2.1MB
  unsigned short* q5    = (unsigned short*)(ws + 41943040);    // 33.5MB
  unsigned short* k5    = (unsigned short*)(ws + 75497472);    // 33.5MB
  unsigned short* v5    = (unsigned short*)(ws + 109051904);   // 33.5MB
  unsigned short* ob    = xb;  // safe alias: xb fully consumed by gemm1 before attn writes

  cvt_kernel<<<8192, 256, 0, stream>>>(x, xb, 2097152);
  transpose_cvt_kernel<<<dim3(96, 32), dim3(32, 8), 0, stream>>>(Wqkv, wqkvT, 1024, 3072);
  transpose_cvt_kernel<<<dim3(32, 32), dim3(32, 8), 0, stream>>>(Wo, woT, 1024, 1024);
  gemm1_kernel<<<dim3(24, 128), 256, 0, stream>>>(xb, wqkvT, fc, fs, q5, k5, v5);
  attn_kernel<<<4096, 256, 0, stream>>>(q5, k5, v5, ob);
  pools_kernel<<<dim3(7, 16, 4), 64, 0, stream>>>(q5, k5, v5, qp, kp, vp, outp);
  gemm2_kernel<<<dim3(8, 128), 256, 0, stream>>>(ob, woT, outp);
}